// Round 1
// baseline (470.227 us; speedup 1.0000x reference)
//
#include <hip/hip_runtime.h>
#include <math.h>

#define BB 2
#define NN 2048
#define KK 30
#define NRBF 16
#define V_DIM 213
#define E_DIM 480
#define NODES (BB*NN)

// ---------- small helpers ----------
__device__ __forceinline__ float sgnf(float x){ return (x>0.f)?1.f:((x<0.f)?-1.f:0.f); }

__device__ __forceinline__ void cross3(const float* a, const float* b, float* c){
  c[0]=a[1]*b[2]-a[2]*b[1];
  c[1]=a[2]*b[0]-a[0]*b[2];
  c[2]=a[0]*b[1]-a[1]*b[0];
}
__device__ __forceinline__ void norm3e(float* v){ // v / max(||v||, 1e-8)
  float n = sqrtf(v[0]*v[0]+v[1]*v[1]+v[2]*v[2]);
  float inv = 1.0f/fmaxf(n,1e-8f);
  v[0]*=inv; v[1]*=inv; v[2]*=inv;
}
__device__ __forceinline__ float dot3(const float* a, const float* b){
  return a[0]*b[0]+a[1]*b[1]+a[2]*b[2];
}

// Given atoms p[12]=N,Ca,C,O of a residue, produce full[30]:
// [0..11]=N,Ca,C,O  [12..14]=Cb  [15..17]=V0  [18..20]=V1  [21..29]=Q rows (b1,n0,b1xn0)
__device__ __forceinline__ void node_derived(const float* p, const float (*va)[3],
                                             float* full, int isLast){
  for(int i=0;i<12;i++) full[i]=p[i];
  float bv[3],cv[3],av[3];
  for(int c=0;c<3;c++){ bv[c]=p[3+c]-p[c]; cv[c]=p[6+c]-p[3+c]; }
  cross3(bv,cv,av);
  for(int c=0;c<3;c++)
    full[12+c] = -0.58273431f*av[c] + 0.56802827f*bv[c] - 0.54067466f*cv[c] + p[3+c];
  for(int i=0;i<2;i++)
    for(int c=0;c<3;c++)
      full[15+3*i+c] = va[i][0]*av[c] + va[i][1]*bv[c] + va[i][2]*cv[c] + p[3+c];
  if (isLast){
    for(int i=0;i<9;i++) full[21+i]=0.f;   // padded Q row for last node
  } else {
    float u0[3],u1[3];
    for(int c=0;c<3;c++){ u0[c]=bv[c]; u1[c]=cv[c]; }
    norm3e(u0); norm3e(u1);
    float n0[3]; cross3(u0,u1,n0); norm3e(n0);
    float b1[3]; for(int c=0;c<3;c++) b1[c]=u0[c]-u1[c];
    norm3e(b1);
    float c2[3]; cross3(b1,n0,c2);
    for(int c=0;c<3;c++){ full[21+c]=b1[c]; full[24+c]=n0[c]; full[27+c]=c2[c]; }
  }
}

// atom indices: N=0,Ca=1,C=2,O=3,Cb=4,V0=5,V1=6
__device__ __constant__ int c_epA[29] = {1,1,2,1,0,4,1,4,0,4,3,4,2,4,1,3,2,2,0,2,3,0,0,3,3, 5,6,6,5};
__device__ __constant__ int c_epB[29] = {1,2,1,0,1,1,4,0,4,3,4,2,4,4,3,1,2,0,2,3,2,0,3,0,3, 5,6,5,6};
__device__ __constant__ int c_npA[12] = {1,1,1,0,0,3,1,4,4,2,6,5};
__device__ __constant__ int c_npB[12] = {0,2,3,2,3,2,4,0,3,4,5,6};

// ---------- kernel 1: top-k neighbor indices (bit-exact distances) ----------
__global__ __launch_bounds__(256) void topk_kernel(const float* __restrict__ X,
                                                   const float* __restrict__ mask,
                                                   float* __restrict__ outIdx){
  __shared__ float sx[NN], sy[NN], sz[NN], smk[NN];
  __shared__ float wv[4];
  __shared__ int   wi[4];
  __shared__ float srmax;
  __shared__ int   swin;
  __shared__ int   winners[KK];

  const int t = threadIdx.x;
  const int row = blockIdx.x;
  const int b = row / NN, n = row % NN;
  const float* Xb = X + (size_t)b*NN*12;
  const float* mb = mask + (size_t)b*NN;

  for (int i=t;i<NN;i+=256){
    sx[i]=Xb[i*12+3]; sy[i]=Xb[i*12+4]; sz[i]=Xb[i*12+5];
    smk[i]=mb[i];
  }
  __syncthreads();

  const float cx=sx[n], cy=sy[n], cz=sz[n], mn=smk[n];
  float dval[8];
  float lmax = -1e30f;
  #pragma unroll
  for (int s=0;s<8;s++){
    int i = s*256+t;
    float dx=__fsub_rn(sx[i],cx), dy=__fsub_rn(sy[i],cy), dz=__fsub_rn(sz[i],cz);
    float ss=__fadd_rn(__fadd_rn(__fadd_rn(__fmul_rn(dx,dx),__fmul_rn(dy,dy)),
                                 __fmul_rn(dz,dz)), 1e-6f);
    float d = __fsqrt_rn(ss);
    float m2 = __fmul_rn(smk[i], mn);
    float om = __fsub_rn(1.0f, m2);
    float D  = __fadd_rn(__fmul_rn(om,10000.0f), __fmul_rn(m2,d));
    dval[s]=D;
    lmax = fmaxf(lmax, D);
  }
  // row max (for D_adj; no-op when mask==1 since (1-m2)==0 exactly)
  for (int off=32; off; off>>=1) lmax = fmaxf(lmax, __shfl_down(lmax, off));
  if ((t&63)==0) wv[t>>6]=lmax;
  __syncthreads();
  if (t==0) srmax = fmaxf(fmaxf(wv[0],wv[1]), fmaxf(wv[2],wv[3]));
  __syncthreads();
  const float radd = __fadd_rn(srmax, 1.0f);
  #pragma unroll
  for (int s=0;s<8;s++){
    int i = s*256+t;
    float m2 = __fmul_rn(smk[i], mn);
    float om = __fsub_rn(1.0f, m2);
    dval[s] = __fadd_rn(dval[s], __fmul_rn(om, radd));
  }
  __syncthreads();

  // 30x lexicographic argmin (ties -> smaller index, matching lax.top_k)
  for (int k=0;k<KK;k++){
    float v = 1e38f; int bi = 0x7fffffff;
    #pragma unroll
    for (int s=0;s<8;s++){
      int i = s*256+t;
      if (dval[s] < v || (dval[s]==v && i<bi)){ v=dval[s]; bi=i; }
    }
    for (int off=32; off; off>>=1){
      float ov = __shfl_down(v, off);
      int   oi = __shfl_down(bi, off);
      if (ov < v || (ov==v && oi<bi)){ v=ov; bi=oi; }
    }
    if ((t&63)==0){ wv[t>>6]=v; wi[t>>6]=bi; }
    __syncthreads();
    if (t==0){
      float bv2=wv[0]; int bj=wi[0];
      for (int w=1;w<4;w++) if (wv[w]<bv2 || (wv[w]==bv2 && wi[w]<bj)){ bv2=wv[w]; bj=wi[w]; }
      swin=bj; winners[k]=bj;
    }
    __syncthreads();
    int win = swin;
    if ((win & 255) == t) dval[win>>8] = 1e38f;
    __syncthreads();
  }
  if (t < KK) outIdx[(size_t)row*KK + t] = (float)winners[t];
}

// ---------- kernel 2: per-node features V (213 per node) ----------
__global__ void nodev_kernel(const float* __restrict__ X, const float* __restrict__ vatoms,
                             float* __restrict__ outV){
  int node = blockIdx.x*blockDim.x + threadIdx.x;
  if (node >= NODES) return;
  const int b = node/NN, n = node%NN;

  float va[2][3];
  for(int i=0;i<2;i++){
    float x=vatoms[3*i],y=vatoms[3*i+1],z=vatoms[3*i+2];
    float inv=1.f/sqrtf(x*x+y*y+z*z);
    va[i][0]=x*inv; va[i][1]=y*inv; va[i][2]=z*inv;
  }
  float p[12];
  { const float* q = X + (size_t)node*12; for(int i=0;i<12;i++) p[i]=q[i]; }
  float full[30];
  node_derived(p, va, full, n==NN-1);

  float* vout = outV + (size_t)node*V_DIM;

  // V_dist: 12 blocks x 16 RBF
  for (int blk=0; blk<12; blk++){
    const float* a=&full[3*c_npA[blk]];
    const float* c=&full[3*c_npB[blk]];
    float dx=a[0]-c[0], dy=a[1]-c[1], dz=a[2]-c[2];
    float D = sqrtf(dx*dx+dy*dy+dz*dz+1e-6f);
    #pragma unroll
    for (int r=0;r<NRBF;r++){
      float t2 = (D - (20.0f/15.0f)*(float)r)*0.8f;
      vout[blk*16+r] = __expf(-t2*t2);
    }
  }

  // dihedrals + bond angles: chain X3 of (N,Ca,C), window m = 3n-1..3n+4
  float P[6][3];
  for (int o=0;o<6;o++){
    int m = 3*n-1+o;
    if (m>=0 && m<3*NN){
      int res=m/3, at=m-3*res;
      const float* qq = X + ((size_t)b*NN+res)*12 + at*3;
      P[o][0]=qq[0]; P[o][1]=qq[1]; P[o][2]=qq[2];
    } else { P[o][0]=P[o][1]=P[o][2]=0.f; }
  }
  float U[5][3];
  for (int o=0;o<5;o++){
    for(int c=0;c<3;c++) U[o][c]=P[o+1][c]-P[o][c];
    norm3e(U[o]);
  }
  float Dv[3], Av[3];
  for (int r=0;r<3;r++){
    int i3 = 3*n + r;
    if (i3>=1 && i3<=3*NN-3){
      float* u0=U[r]; float* u1=U[r+1]; float* u2=U[r+2];
      float n0[3],n1[3];
      cross3(u0,u1,n0); norm3e(n0);
      cross3(u1,u2,n1); norm3e(n1);
      float cosD = fminf(fmaxf(dot3(n0,n1), -1.f+1e-7f), 1.f-1e-7f);
      float v[3]; cross3(n0,n1,v); norm3e(v);
      float s = -(v[0]*u1[0]+v[1]*u1[1]+v[2]*u1[2]);
      Dv[r] = sgnf(s)*acosf(cosD);
      float cosA = fminf(fmaxf(dot3(u0,u1), -1.f+1e-7f), 1.f-1e-7f);
      Av[r] = acosf(cosA);
    } else { Dv[r]=0.f; Av[r]=0.f; }   // padded -> cos=1, sin=0
  }
  for (int r=0;r<3;r++){
    vout[192+r]=cosf(Dv[r]);
    vout[195+r]=sinf(Dv[r]);
    vout[198+r]=cosf(Av[r]);
    vout[201+r]=sinf(Av[r]);
  }

  // V_direct: atoms (N,C,O) - N atom, through Q rows, normalized
  const int aord[3]={0,2,3};
  for (int a2=0;a2<3;a2++){
    int a=aord[a2];
    float d[3]; for(int c=0;c<3;c++) d[c]=full[3*a+c]-full[c];
    float dU[3];
    for(int i=0;i<3;i++)
      dU[i]=full[21+3*i]*d[0]+full[21+3*i+1]*d[1]+full[21+3*i+2]*d[2];
    norm3e(dU);
    for(int c=0;c<3;c++) vout[204+3*a2+c]=dU[c];
  }
}

// ---------- kernel 3: per-edge features E (480 per edge), one block per node ----------
__global__ __launch_bounds__(256) void edge_kernel(const float* __restrict__ X,
                                                   const float* __restrict__ vatoms,
                                                   const float* __restrict__ outIdx,
                                                   float* __restrict__ outE){
  __shared__ float own[32];
  __shared__ float nb[KK][30];
  __shared__ int   jarr[KK];
  __shared__ float dist[KK*29];
  __shared__ float tail[KK][16];
  __shared__ float sva[2][3];

  const int tid = threadIdx.x;
  const int row = blockIdx.x;
  const int b = row/NN, n = row%NN;

  if (tid==0){
    for(int i=0;i<2;i++){
      float x=vatoms[3*i],y=vatoms[3*i+1],z=vatoms[3*i+2];
      float inv=1.f/sqrtf(x*x+y*y+z*z);
      sva[i][0]=x*inv; sva[i][1]=y*inv; sva[i][2]=z*inv;
    }
  }
  if (tid<KK) jarr[tid] = (int)outIdx[(size_t)row*KK+tid];
  __syncthreads();

  if (tid < KK){
    int j = jarr[tid];
    float p[12];
    const float* q = X + ((size_t)b*NN + j)*12;
    for(int i=0;i<12;i++) p[i]=q[i];
    node_derived(p, sva, &nb[tid][0], j==NN-1);
  } else if (tid == KK){
    float p[12];
    const float* q = X + (size_t)row*12;
    for(int i=0;i<12;i++) p[i]=q[i];
    node_derived(p, sva, own, n==NN-1);
  }
  __syncthreads();

  // 870 edge distances
  for (int g=tid; g<KK*29; g+=256){
    int k=g/29, c=g-29*k;
    const float* a = &own[3*c_epA[c]];
    const float* bq = &nb[k][3*c_epB[c]];
    float dx=a[0]-bq[0], dy=a[1]-bq[1], dz=a[2]-bq[2];
    dist[g] = sqrtf(dx*dx+dy*dy+dz*dz+1e-6f);
  }

  // q + E_direct tail (16 floats per edge)
  if (tid < KK){
    const int k=tid;
    float R[3][3];
    for(int i=0;i<3;i++)for(int l=0;l<3;l++){
      float s=0.f;
      for(int j=0;j<3;j++) s += own[21+3*j+i]*nb[k][21+3*j+l];
      R[i][l]=s;
    }
    float Rxx=R[0][0],Ryy=R[1][1],Rzz=R[2][2];
    float m0=0.5f*sqrtf(fabsf(1.f+Rxx-Ryy-Rzz));
    float m1=0.5f*sqrtf(fabsf(1.f-Rxx+Ryy-Rzz));
    float m2=0.5f*sqrtf(fabsf(1.f-Rxx-Ryy+Rzz));
    float qx=sgnf(R[2][1]-R[1][2])*m0;
    float qy=sgnf(R[0][2]-R[2][0])*m1;
    float qz=sgnf(R[1][0]-R[0][1])*m2;
    float w =0.5f*sqrtf(fmaxf(1.f+Rxx+Ryy+Rzz,0.f));
    float inv=1.f/fmaxf(sqrtf(qx*qx+qy*qy+qz*qz+w*w),1e-8f);
    tail[k][0]=qx*inv; tail[k][1]=qy*inv; tail[k][2]=qz*inv; tail[k][3]=w*inv;

    const int aord[4]={1,0,2,3};   // Ca,N,C,O
    for (int a2=0;a2<4;a2++){
      int a=aord[a2];
      float d[3]; for(int c=0;c<3;c++) d[c]=nb[k][3*a+c]-own[c];
      float dU[3];
      for(int i=0;i<3;i++)
        dU[i]=own[21+3*i]*d[0]+own[21+3*i+1]*d[1]+own[21+3*i+2]*d[2];
      norm3e(dU);
      tail[k][4+3*a2+0]=dU[0]; tail[k][4+3*a2+1]=dU[1]; tail[k][4+3*a2+2]=dU[2];
    }
  }
  __syncthreads();

  // coalesced contiguous write of the node's 30x480 E row
  float* eb = outE + (size_t)row*KK*E_DIM;
  for (int g=tid; g<KK*E_DIM; g+=256){
    int k=g/E_DIM, f=g-E_DIM*k;
    float val;
    if (f < 464){
      int c=f>>4, r=f&15;
      float t2 = (dist[k*29+c] - (20.0f/15.0f)*(float)r)*0.8f;
      val = __expf(-t2*t2);
    } else {
      val = tail[k][f-464];
    }
    eb[g]=val;
  }
}

// ---------- launch ----------
extern "C" void kernel_launch(void* const* d_in, const int* in_sizes, int n_in,
                              void* d_out, int out_size, void* d_ws, size_t ws_size,
                              hipStream_t stream) {
  (void)in_sizes; (void)n_in; (void)out_size; (void)d_ws; (void)ws_size;
  const float* X    = (const float*)d_in[0];
  const float* mask = (const float*)d_in[1];
  const float* vat  = (const float*)d_in[2];
  float* out = (float*)d_out;

  float* outV   = out;
  float* outE   = out + (size_t)NODES*V_DIM;
  float* outIdx = out + (size_t)NODES*V_DIM + (size_t)NODES*KK*E_DIM;

  hipLaunchKernelGGL(topk_kernel,  dim3(NODES), dim3(256), 0, stream, X, mask, outIdx);
  hipLaunchKernelGGL(nodev_kernel, dim3((NODES+255)/256), dim3(256), 0, stream, X, vat, outV);
  hipLaunchKernelGGL(edge_kernel,  dim3(NODES), dim3(256), 0, stream, X, vat, outIdx, outE);
}

// Round 2
// 292.313 us; speedup vs baseline: 1.6086x; 1.6086x over previous
//
#include <hip/hip_runtime.h>
#include <math.h>

#define BB 2
#define NN 2048
#define KK 30
#define NRBF 16
#define V_DIM 213
#define E_DIM 480
#define NODES (BB*NN)

typedef unsigned long long u64;
typedef unsigned int u32;

// ---------- small helpers ----------
__device__ __forceinline__ float sgnf(float x){ return (x>0.f)?1.f:((x<0.f)?-1.f:0.f); }

__device__ __forceinline__ void cross3(const float* a, const float* b, float* c){
  c[0]=a[1]*b[2]-a[2]*b[1];
  c[1]=a[2]*b[0]-a[0]*b[2];
  c[2]=a[0]*b[1]-a[1]*b[0];
}
__device__ __forceinline__ void norm3e(float* v){ // v / max(||v||, 1e-8)
  float n = sqrtf(v[0]*v[0]+v[1]*v[1]+v[2]*v[2]);
  float inv = 1.0f/fmaxf(n,1e-8f);
  v[0]*=inv; v[1]*=inv; v[2]*=inv;
}
__device__ __forceinline__ float dot3(const float* a, const float* b){
  return a[0]*b[0]+a[1]*b[1]+a[2]*b[2];
}

// Given atoms p[12]=N,Ca,C,O of a residue, produce full[30]:
// [0..11]=N,Ca,C,O  [12..14]=Cb  [15..17]=V0  [18..20]=V1  [21..29]=Q rows (b1,n0,b1xn0)
__device__ __forceinline__ void node_derived(const float* p, const float (*va)[3],
                                             float* full, int isLast){
  for(int i=0;i<12;i++) full[i]=p[i];
  float bv[3],cv[3],av[3];
  for(int c=0;c<3;c++){ bv[c]=p[3+c]-p[c]; cv[c]=p[6+c]-p[3+c]; }
  cross3(bv,cv,av);
  for(int c=0;c<3;c++)
    full[12+c] = -0.58273431f*av[c] + 0.56802827f*bv[c] - 0.54067466f*cv[c] + p[3+c];
  for(int i=0;i<2;i++)
    for(int c=0;c<3;c++)
      full[15+3*i+c] = va[i][0]*av[c] + va[i][1]*bv[c] + va[i][2]*cv[c] + p[3+c];
  if (isLast){
    for(int i=0;i<9;i++) full[21+i]=0.f;   // padded Q row for last node
  } else {
    float u0[3],u1[3];
    for(int c=0;c<3;c++){ u0[c]=bv[c]; u1[c]=cv[c]; }
    norm3e(u0); norm3e(u1);
    float n0[3]; cross3(u0,u1,n0); norm3e(n0);
    float b1[3]; for(int c=0;c<3;c++) b1[c]=u0[c]-u1[c];
    norm3e(b1);
    float c2[3]; cross3(b1,n0,c2);
    for(int c=0;c<3;c++){ full[21+c]=b1[c]; full[24+c]=n0[c]; full[27+c]=c2[c]; }
  }
}

// atom indices: N=0,Ca=1,C=2,O=3,Cb=4,V0=5,V1=6
__device__ __constant__ int c_epA[29] = {1,1,2,1,0,4,1,4,0,4,3,4,2,4,1,3,2,2,0,2,3,0,0,3,3, 5,6,6,5};
__device__ __constant__ int c_epB[29] = {1,2,1,0,1,1,4,0,4,3,4,2,4,4,3,1,2,0,2,3,2,0,3,0,3, 5,6,5,6};
__device__ __constant__ int c_npA[12] = {1,1,1,0,0,3,1,4,4,2,6,5};
__device__ __constant__ int c_npB[12] = {0,2,3,2,3,2,4,0,3,4,5,6};

// ---------- kernel 1: top-k via histogram prune + rank sort ----------
#define NBIN 2048
#define BINSHIFT 21   // bin = float_bits >> 21 (sign0 + exp8 + mant2)

__global__ __launch_bounds__(256) void topk_kernel(const float* __restrict__ X,
                                                   const float* __restrict__ mask,
                                                   float* __restrict__ outIdx){
  // bins stored transposed: logical bin b at LDS index (b&7)*256 + (b>>3)
  __shared__ u32 bins[NBIN];
  __shared__ u64 cand[NN];
  __shared__ float wred[4];
  __shared__ u32 wsum[4];
  __shared__ int s_cutbin;
  __shared__ u32 s_m;

  const int t = threadIdx.x;
  const int row = blockIdx.x;
  const int b = row / NN, n = row % NN;
  const int w = t>>6, l = t&63;

  for (int i=t;i<NBIN;i+=256) bins[i]=0;
  if (t==0) s_m=0;

  const float* Xb = X + (size_t)b*NN*12;
  const float* mb = mask + (size_t)b*NN;
  const float cx=Xb[n*12+3], cy=Xb[n*12+4], cz=Xb[n*12+5], mn=mb[n];

  // distances, bit-exact IEEE (same op order as the passing round-1 kernel)
  float dval[8];
  float lmax = -1e30f;
  #pragma unroll
  for (int s=0;s<8;s++){
    int i = s*256+t;
    const float* p = Xb + i*12;
    float dx=__fsub_rn(p[3],cx), dy=__fsub_rn(p[4],cy), dz=__fsub_rn(p[5],cz);
    float ss=__fadd_rn(__fadd_rn(__fadd_rn(__fmul_rn(dx,dx),__fmul_rn(dy,dy)),
                                 __fmul_rn(dz,dz)), 1e-6f);
    float d = __fsqrt_rn(ss);
    float m2 = __fmul_rn(mb[i], mn);
    float om = __fsub_rn(1.0f, m2);
    float D  = __fadd_rn(__fmul_rn(om,10000.0f), __fmul_rn(m2,d));
    dval[s]=D;
    lmax = fmaxf(lmax, D);
  }
  #pragma unroll
  for (int off=32; off; off>>=1) lmax = fmaxf(lmax, __shfl_xor(lmax, off));
  if (l==0) wred[w]=lmax;
  __syncthreads();                       // bins zeroed, wred ready
  const float srmax = fmaxf(fmaxf(wred[0],wred[1]), fmaxf(wred[2],wred[3]));
  const float radd = __fadd_rn(srmax, 1.0f);

  u32 keyb[8];
  #pragma unroll
  for (int s=0;s<8;s++){
    int i = s*256+t;
    float m2 = __fmul_rn(mb[i], mn);
    float om = __fsub_rn(1.0f, m2);
    float Dj = __fadd_rn(dval[s], __fmul_rn(om, radd));
    u32 kb = __float_as_uint(Dj);        // Dj >= 0 -> bits order-isomorphic
    keyb[s]=kb;
    u32 bin = kb >> BINSHIFT;
    atomicAdd(&bins[(bin&7)*256 + (bin>>3)], 1u);
  }
  __syncthreads();

  // scan: thread t owns logical bins [8t, 8t+8)
  u32 g8[8]; u32 lsum=0;
  #pragma unroll
  for (int j=0;j<8;j++){ g8[j]=bins[j*256+t]; lsum+=g8[j]; }
  u32 inc=lsum;
  #pragma unroll
  for (int off=1; off<64; off<<=1){
    u32 o = __shfl_up(inc, off);
    if (l >= off) inc += o;
  }
  if (l==63) wsum[w]=inc;
  __syncthreads();
  u32 waveoff=0;
  for (int ww=0; ww<w; ww++) waveoff += wsum[ww];
  u32 run = waveoff + inc - lsum;        // exclusive prefix of this 8-bin group
  #pragma unroll
  for (int j=0;j<8;j++){
    u32 c=g8[j];
    if (run < KK && run + c >= KK) s_cutbin = 8*t+j;   // unique writer
    run += c;
  }
  __syncthreads();
  const int cutbin = s_cutbin;

  // collect candidates (all bins <= cutbin); >=30 guaranteed
  #pragma unroll
  for (int s=0;s<8;s++){
    if ((int)(keyb[s] >> BINSHIFT) <= cutbin){
      u32 slot = atomicAdd(&s_m, 1u);
      cand[slot] = ((u64)keyb[s] << 32) | (u32)(s*256+t);
    }
  }
  __syncthreads();
  const int m = (int)s_m;

  // exact rank (keys unique: idx in low bits) -> scatter; order == lax.top_k
  for (int cix=t; cix<m; cix+=256){
    u64 mykey = cand[cix];
    int rank=0;
    for (int j=0;j<m;j++) rank += (cand[j] < mykey) ? 1 : 0;
    if (rank < KK)
      outIdx[(size_t)row*KK + rank] = (float)(u32)(mykey & 0xffffffffu);
  }
}

// ---------- kernel 2: per-node features V (213) + derived packet to ws ----------
__global__ __launch_bounds__(256) void nodev_kernel(const float* __restrict__ X,
                                                    const float* __restrict__ vatoms,
                                                    float* __restrict__ outV,
                                                    float* __restrict__ packets){
  int node = blockIdx.x*blockDim.x + threadIdx.x;
  if (node >= NODES) return;
  const int b = node/NN, n = node%NN;

  float va[2][3];
  for(int i=0;i<2;i++){
    float x=vatoms[3*i],y=vatoms[3*i+1],z=vatoms[3*i+2];
    float inv=1.f/sqrtf(x*x+y*y+z*z);
    va[i][0]=x*inv; va[i][1]=y*inv; va[i][2]=z*inv;
  }
  float p[12];
  { const float* q = X + (size_t)node*12; for(int i=0;i<12;i++) p[i]=q[i]; }
  float full[30];
  node_derived(p, va, full, n==NN-1);

  if (packets){
    float* pk = packets + (size_t)node*32;
    for (int i=0;i<30;i++) pk[i]=full[i];
    pk[30]=0.f; pk[31]=0.f;
  }

  float* vout = outV + (size_t)node*V_DIM;

  for (int blk=0; blk<12; blk++){
    const float* a=&full[3*c_npA[blk]];
    const float* c=&full[3*c_npB[blk]];
    float dx=a[0]-c[0], dy=a[1]-c[1], dz=a[2]-c[2];
    float D = sqrtf(dx*dx+dy*dy+dz*dz+1e-6f);
    #pragma unroll
    for (int r=0;r<NRBF;r++){
      float t2 = (D - (20.0f/15.0f)*(float)r)*0.8f;
      vout[blk*16+r] = __expf(-t2*t2);
    }
  }

  float P[6][3];
  for (int o=0;o<6;o++){
    int m = 3*n-1+o;
    if (m>=0 && m<3*NN){
      int res=m/3, at=m-3*res;
      const float* qq = X + ((size_t)b*NN+res)*12 + at*3;
      P[o][0]=qq[0]; P[o][1]=qq[1]; P[o][2]=qq[2];
    } else { P[o][0]=P[o][1]=P[o][2]=0.f; }
  }
  float U[5][3];
  for (int o=0;o<5;o++){
    for(int c=0;c<3;c++) U[o][c]=P[o+1][c]-P[o][c];
    norm3e(U[o]);
  }
  float Dv[3], Av[3];
  for (int r=0;r<3;r++){
    int i3 = 3*n + r;
    if (i3>=1 && i3<=3*NN-3){
      float* u0=U[r]; float* u1=U[r+1]; float* u2=U[r+2];
      float n0[3],n1[3];
      cross3(u0,u1,n0); norm3e(n0);
      cross3(u1,u2,n1); norm3e(n1);
      float cosD = fminf(fmaxf(dot3(n0,n1), -1.f+1e-7f), 1.f-1e-7f);
      float v[3]; cross3(n0,n1,v); norm3e(v);
      float s = -(v[0]*u1[0]+v[1]*u1[1]+v[2]*u1[2]);
      Dv[r] = sgnf(s)*acosf(cosD);
      float cosA = fminf(fmaxf(dot3(u0,u1), -1.f+1e-7f), 1.f-1e-7f);
      Av[r] = acosf(cosA);
    } else { Dv[r]=0.f; Av[r]=0.f; }
  }
  for (int r=0;r<3;r++){
    vout[192+r]=cosf(Dv[r]);
    vout[195+r]=sinf(Dv[r]);
    vout[198+r]=cosf(Av[r]);
    vout[201+r]=sinf(Av[r]);
  }

  const int aord[3]={0,2,3};
  for (int a2=0;a2<3;a2++){
    int a=aord[a2];
    float d[3]; for(int c=0;c<3;c++) d[c]=full[3*a+c]-full[c];
    float dU[3];
    for(int i=0;i<3;i++)
      dU[i]=full[21+3*i]*d[0]+full[21+3*i+1]*d[1]+full[21+3*i+2]*d[2];
    norm3e(dU);
    for(int c=0;c<3;c++) vout[204+3*a2+c]=dU[c];
  }
}

// ---------- shared tail math for edge kernels ----------
__device__ __forceinline__ void edge_tail_quat(const float* own, const float* nbk, float* tl){
  float R[3][3];
  for(int i=0;i<3;i++)for(int l2=0;l2<3;l2++){
    float s=0.f;
    for(int j=0;j<3;j++) s += own[21+3*j+i]*nbk[21+3*j+l2];
    R[i][l2]=s;
  }
  float Rxx=R[0][0],Ryy=R[1][1],Rzz=R[2][2];
  float m0=0.5f*sqrtf(fabsf(1.f+Rxx-Ryy-Rzz));
  float m1=0.5f*sqrtf(fabsf(1.f-Rxx+Ryy-Rzz));
  float m2=0.5f*sqrtf(fabsf(1.f-Rxx-Ryy+Rzz));
  float qx=sgnf(R[2][1]-R[1][2])*m0;
  float qy=sgnf(R[0][2]-R[2][0])*m1;
  float qz=sgnf(R[1][0]-R[0][1])*m2;
  float w =0.5f*sqrtf(fmaxf(1.f+Rxx+Ryy+Rzz,0.f));
  float inv=1.f/fmaxf(sqrtf(qx*qx+qy*qy+qz*qz+w*w),1e-8f);
  tl[0]=qx*inv; tl[1]=qy*inv; tl[2]=qz*inv; tl[3]=w*inv;
}

// ---------- kernel 3 (packets path): per-node block, E row (30x480) ----------
__global__ __launch_bounds__(256) void edge_kernel(const float* __restrict__ packets,
                                                   const float* __restrict__ outIdx,
                                                   float* __restrict__ outE){
  __shared__ __align__(16) float own[32];
  __shared__ __align__(16) float nb[KK][32];
  __shared__ int   jarr[KK];
  __shared__ float dist[KK*29];
  __shared__ __align__(16) float tail[KK][16];

  const int tid = threadIdx.x;
  const int row = blockIdx.x;
  const int b = row/NN;

  if (tid<KK) jarr[tid] = (int)outIdx[(size_t)row*KK+tid];
  if (tid>=248){  // own packet: 8 float4s
    int c = tid-248;
    ((float4*)own)[c] = ((const float4*)(packets + (size_t)row*32))[c];
  }
  __syncthreads();

  if (tid < 240){  // neighbor packets: 30 x 8 float4s, coalesced within packet
    int k = tid>>3, c = tid&7;
    ((float4*)&nb[k][0])[c] =
      ((const float4*)(packets + ((size_t)b*NN + jarr[k])*32))[c];
  }
  __syncthreads();

  // 870 edge distances
  for (int g=tid; g<KK*29; g+=256){
    int k=g/29, c=g-29*k;
    const float* a  = &own[3*c_epA[c]];
    const float* bq = &nb[k][3*c_epB[c]];
    float dx=a[0]-bq[0], dy=a[1]-bq[1], dz=a[2]-bq[2];
    dist[g] = sqrtf(dx*dx+dy*dy+dz*dz+1e-6f);
  }

  // tail: quats on lanes 0..29, E_direct on threads 64..183 (30x4 items)
  if (tid < KK){
    edge_tail_quat(own, &nb[tid][0], &tail[tid][0]);
  } else if (tid >= 64 && tid < 64+KK*4){
    const int it = tid-64;
    const int k = it>>2, a2 = it&3;
    const int aord[4]={1,0,2,3};   // Ca,N,C,O
    int a=aord[a2];
    float d[3]; for(int c=0;c<3;c++) d[c]=nb[k][3*a+c]-own[c];
    float dU[3];
    for(int i=0;i<3;i++)
      dU[i]=own[21+3*i]*d[0]+own[21+3*i+1]*d[1]+own[21+3*i+2]*d[2];
    norm3e(dU);
    tail[k][4+3*a2+0]=dU[0]; tail[k][4+3*a2+1]=dU[1]; tail[k][4+3*a2+2]=dU[2];
  }
  __syncthreads();

  // float4 write of the node's 30x480 E row: per edge 116 RBF-quads + 4 tail-quads
  float4* eb = reinterpret_cast<float4*>(outE + (size_t)row*KK*E_DIM);
  for (int g=tid; g<KK*120; g+=256){
    int k=g/120, q=g-120*k;
    float4 v;
    if (q < 116){
      float d = dist[k*29 + (q>>2)];
      float r0 = (float)((q&3)*4);
      float t0 = (d - (20.0f/15.0f)*(r0+0.f))*0.8f;
      float t1 = (d - (20.0f/15.0f)*(r0+1.f))*0.8f;
      float t2 = (d - (20.0f/15.0f)*(r0+2.f))*0.8f;
      float t3 = (d - (20.0f/15.0f)*(r0+3.f))*0.8f;
      v.x=__expf(-t0*t0); v.y=__expf(-t1*t1); v.z=__expf(-t2*t2); v.w=__expf(-t3*t3);
    } else {
      const float* tl = &tail[k][(q-116)*4];
      v = make_float4(tl[0],tl[1],tl[2],tl[3]);
    }
    eb[g]=v;
  }
}

// ---------- kernel 3 fallback (no ws): round-1 proven version ----------
__global__ __launch_bounds__(256) void edge_kernel_fb(const float* __restrict__ X,
                                                      const float* __restrict__ vatoms,
                                                      const float* __restrict__ outIdx,
                                                      float* __restrict__ outE){
  __shared__ float own[32];
  __shared__ float nb[KK][30];
  __shared__ int   jarr[KK];
  __shared__ float dist[KK*29];
  __shared__ float tail[KK][16];
  __shared__ float sva[2][3];

  const int tid = threadIdx.x;
  const int row = blockIdx.x;
  const int b = row/NN, n = row%NN;

  if (tid==0){
    for(int i=0;i<2;i++){
      float x=vatoms[3*i],y=vatoms[3*i+1],z=vatoms[3*i+2];
      float inv=1.f/sqrtf(x*x+y*y+z*z);
      sva[i][0]=x*inv; sva[i][1]=y*inv; sva[i][2]=z*inv;
    }
  }
  if (tid<KK) jarr[tid] = (int)outIdx[(size_t)row*KK+tid];
  __syncthreads();

  if (tid < KK){
    int j = jarr[tid];
    float p[12];
    const float* q = X + ((size_t)b*NN + j)*12;
    for(int i=0;i<12;i++) p[i]=q[i];
    node_derived(p, sva, &nb[tid][0], j==NN-1);
  } else if (tid == KK){
    float p[12];
    const float* q = X + (size_t)row*12;
    for(int i=0;i<12;i++) p[i]=q[i];
    node_derived(p, sva, own, n==NN-1);
  }
  __syncthreads();

  for (int g=tid; g<KK*29; g+=256){
    int k=g/29, c=g-29*k;
    const float* a = &own[3*c_epA[c]];
    const float* bq = &nb[k][3*c_epB[c]];
    float dx=a[0]-bq[0], dy=a[1]-bq[1], dz=a[2]-bq[2];
    dist[g] = sqrtf(dx*dx+dy*dy+dz*dz+1e-6f);
  }

  if (tid < KK){
    const int k=tid;
    edge_tail_quat(own, &nb[k][0], &tail[k][0]);
    const int aord[4]={1,0,2,3};
    for (int a2=0;a2<4;a2++){
      int a=aord[a2];
      float d[3]; for(int c=0;c<3;c++) d[c]=nb[k][3*a+c]-own[c];
      float dU[3];
      for(int i=0;i<3;i++)
        dU[i]=own[21+3*i]*d[0]+own[21+3*i+1]*d[1]+own[21+3*i+2]*d[2];
      norm3e(dU);
      tail[k][4+3*a2+0]=dU[0]; tail[k][4+3*a2+1]=dU[1]; tail[k][4+3*a2+2]=dU[2];
    }
  }
  __syncthreads();

  float* eb = outE + (size_t)row*KK*E_DIM;
  for (int g=tid; g<KK*E_DIM; g+=256){
    int k=g/E_DIM, f=g-E_DIM*k;
    float val;
    if (f < 464){
      int c=f>>4, r=f&15;
      float t2 = (dist[k*29+c] - (20.0f/15.0f)*(float)r)*0.8f;
      val = __expf(-t2*t2);
    } else {
      val = tail[k][f-464];
    }
    eb[g]=val;
  }
}

// ---------- launch ----------
extern "C" void kernel_launch(void* const* d_in, const int* in_sizes, int n_in,
                              void* d_out, int out_size, void* d_ws, size_t ws_size,
                              hipStream_t stream) {
  (void)in_sizes; (void)n_in; (void)out_size;
  const float* X    = (const float*)d_in[0];
  const float* mask = (const float*)d_in[1];
  const float* vat  = (const float*)d_in[2];
  float* out = (float*)d_out;

  float* outV   = out;
  float* outE   = out + (size_t)NODES*V_DIM;
  float* outIdx = out + (size_t)NODES*V_DIM + (size_t)NODES*KK*E_DIM;

  const size_t pk_bytes = (size_t)NODES*32*sizeof(float);
  float* packets = (ws_size >= pk_bytes) ? (float*)d_ws : nullptr;

  hipLaunchKernelGGL(topk_kernel,  dim3(NODES), dim3(256), 0, stream, X, mask, outIdx);
  hipLaunchKernelGGL(nodev_kernel, dim3((NODES+255)/256), dim3(256), 0, stream,
                     X, vat, outV, packets);
  if (packets)
    hipLaunchKernelGGL(edge_kernel, dim3(NODES), dim3(256), 0, stream,
                       packets, outIdx, outE);
  else
    hipLaunchKernelGGL(edge_kernel_fb, dim3(NODES), dim3(256), 0, stream,
                       X, vat, outIdx, outE);
}